// Round 4
// baseline (121.442 us; speedup 1.0000x reference)
//
#include <hip/hip_runtime.h>
#include <hip/hip_bf16.h>

typedef __attribute__((ext_vector_type(8))) short short8;
typedef __attribute__((ext_vector_type(4))) float f32x4;

static constexpr int Bn = 8, Sn = 4096, Dn = 2048, Rn = 64;
static constexpr int NCHUNK = Dn / 64;           // 32 K-chunks of 64
static constexpr int WF_PER_B = NCHUNK * 4096;   // shorts per batch (131072 = 256 KB)

__device__ __forceinline__ unsigned short f2bf(float f) {
    unsigned u = __builtin_bit_cast(unsigned, f);
    u += 0x7FFFu + ((u >> 16) & 1u);             // RTNE
    return (unsigned short)(u >> 16);
}

__device__ __forceinline__ short8 cvt8(const float4& a, const float4& b) {
    // pairs -> v_cvt_pk_bf16_f32
    __hip_bfloat162 p0 = __float22bfloat162_rn(float2{a.x, a.y});
    __hip_bfloat162 p1 = __float22bfloat162_rn(float2{a.z, a.w});
    __hip_bfloat162 p2 = __float22bfloat162_rn(float2{b.x, b.y});
    __hip_bfloat162 p3 = __float22bfloat162_rn(float2{b.z, b.w});
    short8 h;
    h[0] = (short)__builtin_bit_cast(unsigned short, p0.x);
    h[1] = (short)__builtin_bit_cast(unsigned short, p0.y);
    h[2] = (short)__builtin_bit_cast(unsigned short, p1.x);
    h[3] = (short)__builtin_bit_cast(unsigned short, p1.y);
    h[4] = (short)__builtin_bit_cast(unsigned short, p2.x);
    h[5] = (short)__builtin_bit_cast(unsigned short, p2.y);
    h[6] = (short)__builtin_bit_cast(unsigned short, p3.x);
    h[7] = (short)__builtin_bit_cast(unsigned short, p3.y);
    return h;
}

// ---------------- prep: W fp32 [b][k][r] -> bf16, MFMA B-fragment order ----------------
// Wf flat index: (((b*32 + c)*2 + ks)*4 + nt)*512 + lane*8 + f
// holds bf16( W[b][c*64 + ks*32 + (lane>>4)*8 + f][nt*16 + (lane&15)] )
__global__ __launch_bounds__(256) void prep_w(const float* __restrict__ W,
                                              unsigned short* __restrict__ Wf) {
    const int t    = blockIdx.x * 256 + threadIdx.x;   // 0 .. 131071
    const int lane = t & 63;
    const int nt   = (t >> 6) & 3;
    const int ks   = (t >> 8) & 1;
    const int c    = (t >> 9) & 31;
    const int b    = t >> 14;
    const int g    = lane >> 4;
    const int r    = nt * 16 + (lane & 15);
    const float* __restrict__ src =
        W + ((size_t)b * Dn + c * 64 + ks * 32 + g * 8) * Rn + r;
    short8 o;
#pragma unroll
    for (int f = 0; f < 8; ++f) o[f] = (short)f2bf(src[(size_t)f * Rn]);
    *reinterpret_cast<short8*>(Wf + (size_t)t * 8) = o;   // coalesced 16B store
}

// ---------------- main: barrier-free streaming GEMM, A-depth-4 pipeline ----------------
struct ABuf { float4 v0, v1, v2, v3; };

__device__ __forceinline__ void load_a(ABuf& A, const float* p) {
    A.v0 = *reinterpret_cast<const float4*>(p);
    A.v1 = *reinterpret_cast<const float4*>(p + 4);
    A.v2 = *reinterpret_cast<const float4*>(p + 32);
    A.v3 = *reinterpret_cast<const float4*>(p + 36);
}
__device__ __forceinline__ void load_b(short8* Bv, const unsigned short* q) {
#pragma unroll
    for (int i = 0; i < 8; ++i)
        Bv[i] = *reinterpret_cast<const short8*>(q + i * 512);
}
__device__ __forceinline__ void compute_chunk(const ABuf& A, const short8* Bv, f32x4* acc) {
    const short8 h0 = cvt8(A.v0, A.v1);   // ks0: k = g*8 + 0..7
    const short8 h1 = cvt8(A.v2, A.v3);   // ks1
#pragma unroll
    for (int nt = 0; nt < 4; ++nt)
        acc[nt] = __builtin_amdgcn_mfma_f32_16x16x32_bf16(h0, Bv[nt], acc[nt], 0, 0, 0);
#pragma unroll
    for (int nt = 0; nt < 4; ++nt)
        acc[nt] = __builtin_amdgcn_mfma_f32_16x16x32_bf16(h1, Bv[4 + nt], acc[nt], 0, 0, 0);
}

__global__ __launch_bounds__(256, 2)
void lora_main(const float* __restrict__ X, const unsigned short* __restrict__ Wf,
               float* __restrict__ O) {
    const int blk  = blockIdx.x;
    const int b    = blk >> 6;             // 64 blocks per batch
    const int m0   = (blk & 63) * 64;      // BM = 64
    const int tid  = threadIdx.x;
    const int wid  = tid >> 6;
    const int lane = tid & 63;
    const int l15  = lane & 15;
    const int g    = lane >> 4;

    const float* xp = X + (size_t)b * (Sn * Dn)
                        + (size_t)(m0 + wid * 16 + l15) * Dn + g * 8;
    const unsigned short* bp = Wf + (size_t)b * WF_PER_B + lane * 8;

    f32x4 acc[4];
#pragma unroll
    for (int i = 0; i < 4; ++i) acc[i] = f32x4{0.f, 0.f, 0.f, 0.f};

    ABuf A0, A1, A2, A3;
    short8 B0[8], B1[8];
    load_a(A0, xp);
    load_a(A1, xp + 64);
    load_a(A2, xp + 128);
    load_a(A3, xp + 192);
    load_b(B0, bp);
    load_b(B1, bp + 4096);

    for (int c = 0; c < NCHUNK; c += 4) {
        // ---- chunk c+0 : A0, B0 ----
        compute_chunk(A0, B0, acc);
        {   // refill A0 <- chunk c+4, B0 <- chunk c+2
            const float*          xa = (c + 4 < NCHUNK) ? xp + (size_t)(c + 4) * 64 : xp;
            const unsigned short* bq = (c + 2 < NCHUNK) ? bp + (size_t)(c + 2) * 4096 : bp;
            load_a(A0, xa);
            load_b(B0, bq);
        }
        // ---- chunk c+1 : A1, B1 ----
        compute_chunk(A1, B1, acc);
        {   // refill A1 <- chunk c+5, B1 <- chunk c+3
            const float*          xa = (c + 5 < NCHUNK) ? xp + (size_t)(c + 5) * 64 : xp;
            const unsigned short* bq = (c + 3 < NCHUNK) ? bp + (size_t)(c + 3) * 4096 : bp;
            load_a(A1, xa);
            load_b(B1, bq);
        }
        // ---- chunk c+2 : A2, B0 (B0 now holds chunk c+2) ----
        compute_chunk(A2, B0, acc);
        {   // refill A2 <- chunk c+6, B0 <- chunk c+4
            const float*          xa = (c + 6 < NCHUNK) ? xp + (size_t)(c + 6) * 64 : xp;
            const unsigned short* bq = (c + 4 < NCHUNK) ? bp + (size_t)(c + 4) * 4096 : bp;
            load_a(A2, xa);
            load_b(B0, bq);
        }
        // ---- chunk c+3 : A3, B1 (B1 now holds chunk c+3) ----
        compute_chunk(A3, B1, acc);
        {   // refill A3 <- chunk c+7, B1 <- chunk c+5
            const float*          xa = (c + 7 < NCHUNK) ? xp + (size_t)(c + 7) * 64 : xp;
            const unsigned short* bq = (c + 5 < NCHUNK) ? bp + (size_t)(c + 5) * 4096 : bp;
            load_a(A3, xa);
            load_b(B1, bq);
        }
    }

    // epilogue: C/D layout col=lane&15, row=(lane>>4)*4+reg
    float* __restrict__ ob = O + (size_t)b * (Sn * Rn) + (size_t)(m0 + wid * 16) * Rn;
    const int r0 = g * 4;
#pragma unroll
    for (int nt = 0; nt < 4; ++nt) {
#pragma unroll
        for (int r = 0; r < 4; ++r) {
            ob[(size_t)(r0 + r) * Rn + nt * 16 + l15] = acc[nt][r];
        }
    }
}

// ---------------- fallback (LDS-staged, single kernel) if ws is too small ----------------
__global__ __launch_bounds__(256, 2)
void batch_lora_fused(const float* __restrict__ X, const float* __restrict__ W,
                      float* __restrict__ O) {
    __shared__ unsigned short wlds[2 * 4 * 64 * 8];
    const int blk  = blockIdx.x;
    const int b    = blk >> 6;
    const int m0   = (blk & 63) * 64;
    const int tid  = threadIdx.x;
    const int wid  = tid >> 6;
    const int lane = tid & 63;
    const int l15  = lane & 15;
    const int g    = lane >> 4;
    const float* __restrict__ xrow = X + (size_t)b * (Sn * Dn)
                                       + (size_t)(m0 + wid * 16 + l15) * Dn + g * 8;
    const float* __restrict__ wb = W + (size_t)b * (Dn * Rn);
    f32x4 acc[4];
#pragma unroll
    for (int i = 0; i < 4; ++i) acc[i] = f32x4{0.f, 0.f, 0.f, 0.f};
    for (int kb = 0; kb < Dn; kb += 64) {
#pragma unroll
        for (int i = 0; i < 4; ++i) {
            const int e  = 4 * (tid + 256 * i);
            const int kk = e >> 6;
            const int cc = e & 63;
            const float4 w4 = *reinterpret_cast<const float4*>(
                wb + (size_t)(kb + kk) * Rn + cc);
            const int ks = kk >> 5;
            const int k5 = kk & 31;
            const int nt = cc >> 4;
            const int f  = k5 & 7;
            const int lw = 16 * (k5 >> 3) + (cc & 15);
            unsigned short* dst = &wlds[((ks * 4 + nt) * 64 + lw) * 8 + f];
            dst[0 * 8] = f2bf(w4.x); dst[1 * 8] = f2bf(w4.y);
            dst[2 * 8] = f2bf(w4.z); dst[3 * 8] = f2bf(w4.w);
        }
        __syncthreads();
#pragma unroll
        for (int ks = 0; ks < 2; ++ks) {
            const float* ap = xrow + kb + ks * 32;
            const float4 a0 = *reinterpret_cast<const float4*>(ap);
            const float4 a1 = *reinterpret_cast<const float4*>(ap + 4);
            const short8 ahi = cvt8(a0, a1);
#pragma unroll
            for (int nt = 0; nt < 4; ++nt) {
                const short8 bhi = *reinterpret_cast<const short8*>(
                    &wlds[((ks * 4 + nt) * 64 + lane) * 8]);
                acc[nt] = __builtin_amdgcn_mfma_f32_16x16x32_bf16(ahi, bhi, acc[nt], 0, 0, 0);
            }
        }
        __syncthreads();
    }
    float* __restrict__ ob = O + (size_t)b * (Sn * Rn) + (size_t)(m0 + wid * 16) * Rn;
    const int r0 = g * 4;
#pragma unroll
    for (int nt = 0; nt < 4; ++nt)
#pragma unroll
        for (int r = 0; r < 4; ++r)
            ob[(size_t)(r0 + r) * Rn + nt * 16 + l15] = acc[nt][r];
}

extern "C" void kernel_launch(void* const* d_in, const int* in_sizes, int n_in,
                              void* d_out, int out_size, void* d_ws, size_t ws_size,
                              hipStream_t stream) {
    const float* x = (const float*)d_in[0];
    const float* w = (const float*)d_in[1];
    float* out = (float*)d_out;
    const size_t wf_bytes = (size_t)Bn * WF_PER_B * sizeof(unsigned short);  // 2 MiB
    if (ws_size >= wf_bytes) {
        unsigned short* wf = (unsigned short*)d_ws;
        prep_w<<<dim3(512), dim3(256), 0, stream>>>(w, wf);
        lora_main<<<dim3(Bn * (Sn / 64)), dim3(256), 0, stream>>>(x, wf, out);
    } else {
        batch_lora_fused<<<dim3(Bn * (Sn / 64)), dim3(256), 0, stream>>>(x, w, out);
    }
}

// Round 5
// 63.389 us; speedup vs baseline: 1.9158x; 1.9158x over previous
//
#include <hip/hip_runtime.h>
#include <hip/hip_bf16.h>

typedef __attribute__((ext_vector_type(8))) short short8;
typedef __attribute__((ext_vector_type(4))) float f32x4;

static constexpr int Bn = 8, Sn = 4096, Dn = 2048, Rn = 64;
static constexpr int NCHUNK = Dn / 64;           // 32 K-chunks of 64
static constexpr int WF_PER_B = NCHUNK * 4096;   // shorts per batch (131072 = 256 KB)

__device__ __forceinline__ unsigned short f2bf(float f) {
    unsigned u = __builtin_bit_cast(unsigned, f);
    u += 0x7FFFu + ((u >> 16) & 1u);             // RTNE
    return (unsigned short)(u >> 16);
}

__device__ __forceinline__ short8 cvt8(const float4& a, const float4& b) {
    // pairs -> v_cvt_pk_bf16_f32
    __hip_bfloat162 p0 = __float22bfloat162_rn(float2{a.x, a.y});
    __hip_bfloat162 p1 = __float22bfloat162_rn(float2{a.z, a.w});
    __hip_bfloat162 p2 = __float22bfloat162_rn(float2{b.x, b.y});
    __hip_bfloat162 p3 = __float22bfloat162_rn(float2{b.z, b.w});
    short8 h;
    h[0] = (short)__builtin_bit_cast(unsigned short, p0.x);
    h[1] = (short)__builtin_bit_cast(unsigned short, p0.y);
    h[2] = (short)__builtin_bit_cast(unsigned short, p1.x);
    h[3] = (short)__builtin_bit_cast(unsigned short, p1.y);
    h[4] = (short)__builtin_bit_cast(unsigned short, p2.x);
    h[5] = (short)__builtin_bit_cast(unsigned short, p2.y);
    h[6] = (short)__builtin_bit_cast(unsigned short, p3.x);
    h[7] = (short)__builtin_bit_cast(unsigned short, p3.y);
    return h;
}

// ---------------- prep: W fp32 [b][k][r] -> bf16, MFMA B-fragment order ----------------
// Wf flat index: (((b*32 + c)*2 + ks)*4 + nt)*512 + lane*8 + f
// holds bf16( W[b][c*64 + ks*32 + (lane>>4)*8 + f][nt*16 + (lane&15)] )
__global__ __launch_bounds__(256) void prep_w(const float* __restrict__ W,
                                              unsigned short* __restrict__ Wf) {
    const int t    = blockIdx.x * 256 + threadIdx.x;   // 0 .. 131071
    const int lane = t & 63;
    const int nt   = (t >> 6) & 3;
    const int ks   = (t >> 8) & 1;
    const int c    = (t >> 9) & 31;
    const int b    = t >> 14;
    const int g    = lane >> 4;
    const int r    = nt * 16 + (lane & 15);
    const float* __restrict__ src =
        W + ((size_t)b * Dn + c * 64 + ks * 32 + g * 8) * Rn + r;
    short8 o;
#pragma unroll
    for (int f = 0; f < 8; ++f) o[f] = (short)f2bf(src[(size_t)f * Rn]);
    *reinterpret_cast<short8*>(Wf + (size_t)t * 8) = o;   // coalesced 16B store
}

// ---------------- main: barrier-free streaming, K-split 2, 16 waves/CU ----------------
struct ABuf { float4 v0, v1, v2, v3; };

__device__ __forceinline__ void load_a(ABuf& A, const float* p) {
    A.v0 = *reinterpret_cast<const float4*>(p);
    A.v1 = *reinterpret_cast<const float4*>(p + 4);
    A.v2 = *reinterpret_cast<const float4*>(p + 32);
    A.v3 = *reinterpret_cast<const float4*>(p + 36);
}
__device__ __forceinline__ void load_b(short8* Bv, const unsigned short* q) {
#pragma unroll
    for (int i = 0; i < 8; ++i)
        Bv[i] = *reinterpret_cast<const short8*>(q + i * 512);
}
__device__ __forceinline__ void compute_chunk(const ABuf& A, const short8* Bv, f32x4* acc) {
    const short8 h0 = cvt8(A.v0, A.v1);   // ks0: k = g*8 + 0..7
    const short8 h1 = cvt8(A.v2, A.v3);   // ks1
#pragma unroll
    for (int nt = 0; nt < 4; ++nt)
        acc[nt] = __builtin_amdgcn_mfma_f32_16x16x32_bf16(h0, Bv[nt], acc[nt], 0, 0, 0);
#pragma unroll
    for (int nt = 0; nt < 4; ++nt)
        acc[nt] = __builtin_amdgcn_mfma_f32_16x16x32_bf16(h1, Bv[4 + nt], acc[nt], 0, 0, 0);
}

__global__ __launch_bounds__(512, 4)
void lora_main_ks(const float* __restrict__ X, const unsigned short* __restrict__ Wf,
                  float* __restrict__ O) {
    __shared__ float red[64 * 64];         // 16 KB partial-sum exchange

    const int blk  = blockIdx.x;
    const int b    = blk >> 6;             // 64 blocks per batch
    const int m0   = (blk & 63) * 64;      // BM = 64
    const int tid  = threadIdx.x;
    const int wid  = tid >> 6;             // 0..7
    const int lane = tid & 63;
    const int l15  = lane & 15;
    const int g    = lane >> 4;
    const int kh   = wid >> 2;             // K-half: waves 0-3 -> 0, 4-7 -> 1
    const int wm   = wid & 3;              // M-subtile within block

    const float* xp = X + (size_t)b * (Sn * Dn)
                        + (size_t)(m0 + wm * 16 + l15) * Dn + kh * (Dn / 2) + g * 8;
    const unsigned short* bp = Wf + (size_t)b * WF_PER_B + kh * (WF_PER_B / 2) + lane * 8;

    f32x4 acc[4];
#pragma unroll
    for (int i = 0; i < 4; ++i) acc[i] = f32x4{0.f, 0.f, 0.f, 0.f};

    ABuf A0, A1;
    short8 Bv[8];
    load_a(A0, xp);

    // 16 chunks per K-half, rotated 2 at a time (R2-proven body shape)
    for (int it = 0; it < 8; ++it) {
        load_a(A1, xp + 64);               // prefetch next chunk's A (1-chunk cover)
        load_b(Bv, bp);                    // B chunk c (L2-resident, short cover)
        compute_chunk(A0, Bv, acc);

        const bool last = (it == 7);
        load_a(A0, last ? xp : (xp + 128)); // prefetch chunk c+2 (dummy on last)
        load_b(Bv, bp + 4096);              // B chunk c+1
        compute_chunk(A1, Bv, acc);

        xp += 128;
        bp += 8192;
    }

    // ---- reduce the two K-halves via LDS, then store ----
    const int r0 = g * 4;
    if (kh == 0) {
#pragma unroll
        for (int nt = 0; nt < 4; ++nt)
#pragma unroll
            for (int r = 0; r < 4; ++r)
                red[(wm * 16 + r0 + r) * 64 + nt * 16 + l15] = acc[nt][r];
    }
    __syncthreads();
    if (kh == 1) {
        float* __restrict__ ob = O + (size_t)b * (Sn * Rn) + (size_t)(m0 + wm * 16) * Rn;
#pragma unroll
        for (int nt = 0; nt < 4; ++nt)
#pragma unroll
            for (int r = 0; r < 4; ++r)
                ob[(size_t)(r0 + r) * Rn + nt * 16 + l15] =
                    acc[nt][r] + red[(wm * 16 + r0 + r) * 64 + nt * 16 + l15];
    }
}

// ---------------- fallback (LDS-staged, single kernel) if ws is too small ----------------
__global__ __launch_bounds__(256, 2)
void batch_lora_fused(const float* __restrict__ X, const float* __restrict__ W,
                      float* __restrict__ O) {
    __shared__ unsigned short wlds[2 * 4 * 64 * 8];
    const int blk  = blockIdx.x;
    const int b    = blk >> 6;
    const int m0   = (blk & 63) * 64;
    const int tid  = threadIdx.x;
    const int wid  = tid >> 6;
    const int lane = tid & 63;
    const int l15  = lane & 15;
    const int g    = lane >> 4;
    const float* __restrict__ xrow = X + (size_t)b * (Sn * Dn)
                                       + (size_t)(m0 + wid * 16 + l15) * Dn + g * 8;
    const float* __restrict__ wb = W + (size_t)b * (Dn * Rn);
    f32x4 acc[4];
#pragma unroll
    for (int i = 0; i < 4; ++i) acc[i] = f32x4{0.f, 0.f, 0.f, 0.f};
    for (int kb = 0; kb < Dn; kb += 64) {
#pragma unroll
        for (int i = 0; i < 4; ++i) {
            const int e  = 4 * (tid + 256 * i);
            const int kk = e >> 6;
            const int cc = e & 63;
            const float4 w4 = *reinterpret_cast<const float4*>(
                wb + (size_t)(kb + kk) * Rn + cc);
            const int ks = kk >> 5;
            const int k5 = kk & 31;
            const int nt = cc >> 4;
            const int f  = k5 & 7;
            const int lw = 16 * (k5 >> 3) + (cc & 15);
            unsigned short* dst = &wlds[((ks * 4 + nt) * 64 + lw) * 8 + f];
            dst[0 * 8] = f2bf(w4.x); dst[1 * 8] = f2bf(w4.y);
            dst[2 * 8] = f2bf(w4.z); dst[3 * 8] = f2bf(w4.w);
        }
        __syncthreads();
#pragma unroll
        for (int ks = 0; ks < 2; ++ks) {
            const float* ap = xrow + kb + ks * 32;
            const float4 a0 = *reinterpret_cast<const float4*>(ap);
            const float4 a1 = *reinterpret_cast<const float4*>(ap + 4);
            const short8 ahi = cvt8(a0, a1);
#pragma unroll
            for (int nt = 0; nt < 4; ++nt) {
                const short8 bhi = *reinterpret_cast<const short8*>(
                    &wlds[((ks * 4 + nt) * 64 + lane) * 8]);
                acc[nt] = __builtin_amdgcn_mfma_f32_16x16x32_bf16(ahi, bhi, acc[nt], 0, 0, 0);
            }
        }
        __syncthreads();
    }
    float* __restrict__ ob = O + (size_t)b * (Sn * Rn) + (size_t)(m0 + wid * 16) * Rn;
    const int r0 = g * 4;
#pragma unroll
    for (int nt = 0; nt < 4; ++nt)
#pragma unroll
        for (int r = 0; r < 4; ++r)
            ob[(size_t)(r0 + r) * Rn + nt * 16 + l15] = acc[nt][r];
}

extern "C" void kernel_launch(void* const* d_in, const int* in_sizes, int n_in,
                              void* d_out, int out_size, void* d_ws, size_t ws_size,
                              hipStream_t stream) {
    const float* x = (const float*)d_in[0];
    const float* w = (const float*)d_in[1];
    float* out = (float*)d_out;
    const size_t wf_bytes = (size_t)Bn * WF_PER_B * sizeof(unsigned short);  // 2 MiB
    if (ws_size >= wf_bytes) {
        unsigned short* wf = (unsigned short*)d_ws;
        prep_w<<<dim3(512), dim3(256), 0, stream>>>(w, wf);
        lora_main_ks<<<dim3(Bn * (Sn / 64)), dim3(512), 0, stream>>>(x, wf, out);
    } else {
        batch_lora_fused<<<dim3(Bn * (Sn / 64)), dim3(256), 0, stream>>>(x, w, out);
    }
}